// Round 11
// baseline (370.599 us; speedup 1.0000x reference)
//
#include <hip/hip_runtime.h>

#define B_  1024
#define T_  128
#define V_  89
#define H_  256
#define NB2 256          // fused-kernel blocks
#define PT_ 4            // timesteps per phase
#define NPH 32           // phases

typedef __attribute__((ext_vector_type(8))) short bf16x8;
typedef __attribute__((ext_vector_type(4))) float f32x4;
typedef __attribute__((ext_vector_type(4))) unsigned short u16x4;

__device__ __forceinline__ short f2bs(float f){
    unsigned u = __float_as_uint(f);
    unsigned r = (u + 0x7FFFu + ((u>>16)&1u)) >> 16;
    return (short)r;
}
__device__ __forceinline__ float s2f(unsigned short s){
    return __uint_as_float(((unsigned)s) << 16);
}
__device__ __forceinline__ float sig_(float x){ return 1.f/(1.f+__expf(-x)); }
__device__ __forceinline__ float tanh_(float x){ return 2.f/(1.f+__expf(-2.f*x)) - 1.f; }

// ---------------------------------------------------------------- W_hh fp32 -> fp8 [768][256] linear
__global__ __launch_bounds__(256) void k_cvt_fp8(
    const float* __restrict__ src, unsigned char* __restrict__ dst, int n)
{
    int i = blockIdx.x*256 + threadIdx.x;
    if (i*4 >= n) return;
    float f0 = src[i*4+0], f1 = src[i*4+1], f2 = src[i*4+2], f3 = src[i*4+3];
    int w = __builtin_amdgcn_cvt_pk_fp8_f32(f0, f1, 0, false);
    w     = __builtin_amdgcn_cvt_pk_fp8_f32(f2, f3, w, true);
    ((int*)dst)[i] = w;
}

// ---------------------------------------------------------------- W_ih+b_ih -> fp8 fragment-major
// chunk idx = (((WV*3+g)*6+kt)*4+g8)*16 + l15 ; chunk = 8 fp8 of row n=g*256+WV*16+l15,
// k-bytes kt*32+g8*8 .. +7 (k: 0..177 = W_ih, 178 = bias, else 0). WV 0..15.
__global__ __launch_bounds__(256) void k_prep_wih8(
    const float* __restrict__ W_ih, const float* __restrict__ b_ih,
    unsigned char* __restrict__ dst)
{
    int i = blockIdx.x*256 + threadIdx.x;      // chunk id, total 18432
    if (i >= 18432) return;
    int l15 = i & 15, t = i >> 4;
    int g8 = t & 3; t >>= 2;
    int kt = t % 6; t /= 6;
    int g = t % 3, WV = t / 3;
    int n = g*256 + WV*16 + l15;
    float f[8];
    #pragma unroll
    for (int j = 0; j < 8; ++j) {
        int k = kt*32 + g8*8 + j;
        f[j] = (k < 178) ? W_ih[(size_t)n*178 + k] : (k == 178 ? b_ih[n] : 0.f);
    }
    int w0 = __builtin_amdgcn_cvt_pk_fp8_f32(f[0], f[1], 0, false);
    w0     = __builtin_amdgcn_cvt_pk_fp8_f32(f[2], f[3], w0, true);
    int w1 = __builtin_amdgcn_cvt_pk_fp8_f32(f[4], f[5], 0, false);
    w1     = __builtin_amdgcn_cvt_pk_fp8_f32(f[6], f[7], w1, true);
    ((int*)dst)[i*2]   = w0;
    ((int*)dst)[i*2+1] = w1;
}

// ---------------------------------------------------------------- W_h+b_h -> bf16 [256][96]
__global__ __launch_bounds__(256) void k_prep_whp(
    const float* __restrict__ W_h, const float* __restrict__ b_h,
    short* __restrict__ dst)
{
    int i = blockIdx.x*256 + threadIdx.x;
    if (i >= 256*96) return;
    int n = i / 96, k = i - n*96;
    float v = (k < V_) ? W_h[(size_t)n*V_ + k] : (k == V_ ? b_h[n] : 0.f);
    dst[i] = f2bs(v);
}

// ---------------------------------------------------------------- gamma_h producer
// gdv u16x4 idx = (p*1024 + bx*4 + g8)*256 + col ; v[rr] = gamma(b, t=p*4+rr, col)
__global__ __launch_bounds__(256) void k_gammah(
    const float* __restrict__ deltas, const short* __restrict__ whp,
    unsigned short* __restrict__ gdv)
{
    __shared__ short dl2[16*104] __attribute__((aligned(16)));
    int tid = threadIdx.x;
    int bx = blockIdx.x, p = blockIdx.y;
    for (int i = tid; i < 16*96; i += 256) {
        int m = i / 96, k = i - m*96;
        int b = bx*4 + (m>>2), t = p*4 + (m&3);
        float val = 0.f;
        if (k < V_)       val = deltas[((size_t)b*T_ + t)*V_ + k];
        else if (k == V_) val = 1.0f;
        dl2[m*104 + k] = f2bs(val);
    }
    __syncthreads();
    int lane = tid & 63, wv = tid >> 6;
    int l15 = lane & 15, g8 = lane >> 4;
    f32x4 z4 = {0.f,0.f,0.f,0.f};
    f32x4 acc[4];
    #pragma unroll
    for (int nt = 0; nt < 4; ++nt) acc[nt] = z4;
    #pragma unroll
    for (int kt = 0; kt < 3; ++kt) {
        bf16x8 a = *(const bf16x8*)&dl2[l15*104 + kt*32 + g8*8];
        #pragma unroll
        for (int nt = 0; nt < 4; ++nt) {
            int cg = wv*64 + nt*16 + l15;
            bf16x8 bb = *(const bf16x8*)(whp + (size_t)cg*96 + kt*32 + g8*8);
            acc[nt] = __builtin_amdgcn_mfma_f32_16x16x32_bf16(a, bb, acc[nt], 0,0,0);
        }
    }
    #pragma unroll
    for (int nt = 0; nt < 4; ++nt) {
        int cg = wv*64 + nt*16 + l15;
        u16x4 v;
        #pragma unroll
        for (int rr = 0; rr < 4; ++rr)
            v[rr] = (unsigned short)f2bs(__expf(-fmaxf(acc[nt][rr], 0.f)));
        ((u16x4*)gdv)[((size_t)(p*1024 + bx*4 + g8))*256 + cg] = v;
    }
}

// ---------------------------------------------------------------- fused kernel
// 256 blocks x 512 thr (8 waves). Lane owns cols c0=wv*16+l15, c1=c0+128; batch row g8.
// W_hh r,z gates: fp8 in LDS (131 KB, XOR-swizzled). W_hh n gate: 32 VGPR (pinned).
// W_ih: streamed per phase from L2 (fragment-major coalesced layout).
__global__ __launch_bounds__(512, 2)
void k_fused(
    const float* __restrict__ x, const float* __restrict__ mask,
    const float* __restrict__ deltas, const float* __restrict__ meanset,
    const float* __restrict__ W_x, const float* __restrict__ b_x,
    const unsigned char* __restrict__ wihT, const unsigned char* __restrict__ whh8,
    const unsigned short* __restrict__ gdv, const float* __restrict__ b_hh,
    const float* __restrict__ W_cls, const float* __restrict__ b_cls,
    float* __restrict__ ximp, float* __restrict__ numpart, float* __restrict__ denpart,
    float* __restrict__ yout, float* __restrict__ yscore)
{
    __shared__ unsigned char whL[512*256];                             // r,z gates, swizzled
    __shared__ unsigned char xl[16*200] __attribute__((aligned(16)));  // fp8 [x_h|m|1|0]
    __shared__ unsigned char hlds[2][4*272] __attribute__((aligned(16)));
    __shared__ float lossn[PT_][360], lossd[PT_][360];
    __shared__ float yred[4][8];

    int tid = threadIdx.x;
    int lane = tid & 63, wv = tid >> 6;        // wv 0..7
    int l15 = lane & 15, g8 = lane >> 4;
    int blk = blockIdx.x;
    int c0 = wv*16 + l15;                      // 0..127
    int c1 = c0 + 128;                         // 128..255
    int mR = (c0 & 31) << 3;                   // swizzle mask (same for all 4 owned rows)

    // ---- stage W_hh r,z into LDS with XOR swizzle (coalesced global reads)
    for (int idx = tid; idx < 512*32; idx += 512) {
        int row = idx >> 5, j = idx & 31;
        long v = *(const long*)(whh8 + (size_t)row*256 + j*8);
        *(long*)&whL[row*256 + ((j*8) ^ ((row & 31) << 3))] = v;
    }
    // static pads of xl
    for (int i = tid; i < 16*14; i += 512) {
        int r = i / 14, k = 178 + (i - r*14);
        xl[r*200 + k] = (k == 178) ? 0x38 : 0;   // fp8(1.0)
    }

    // ---- n-gate W_hh in registers (32 VGPR), pinned
    long wfn0[8], wfn1[8];
    #pragma unroll
    for (int kt = 0; kt < 8; ++kt) {
        wfn0[kt] = *(const long*)(whh8 + (size_t)(512 + c0)*256 + kt*32 + g8*8);
        wfn1[kt] = *(const long*)(whh8 + (size_t)(512 + c1)*256 + kt*32 + g8*8);
    }
    #pragma unroll
    for (int kt = 0; kt < 8; ++kt) {
        asm volatile("" : "+v"(wfn0[kt]));
        asm volatile("" : "+v"(wfn1[kt]));
    }

    float bhr0 = b_hh[c0], bhz0 = b_hh[H_ + c0], bhn0 = b_hh[2*H_ + c0];
    float bhr1 = b_hh[c1], bhz1 = b_hh[H_ + c1], bhn1 = b_hh[2*H_ + c1];

    // owners: one per (row, v); 356 threads
    bool own = (tid < 4*V_);
    int r_o = tid / V_, v_o = tid - r_o*V_;
    int b_o = blk*4 + r_o;
    float wxd = 0.f, bx = 0.f, mnv = 0.f, last = 0.f;
    if (own) { wxd = W_x[v_o*V_ + v_o]; bx = b_x[v_o]; mnv = meanset[v_o]; }

    // wih fragment-major bases (chunk units of 8B)
    const long* wT = (const long*)wihT;
    int iw0 = wv*1152 + g8*16 + l15;            // WV = wv
    int iw1 = (wv + 8)*1152 + g8*16 + l15;      // WV = wv+8 (c1)

    float h0 = 0.f, h1 = 0.f;

    // ---- prologue: inputs + gamma for phase 0
    float xv[PT_], mv[PT_], dvv[PT_];
    if (own) {
        const float* xb = x      + ((size_t)b_o*T_)*V_ + v_o;
        const float* mb = mask   + ((size_t)b_o*T_)*V_ + v_o;
        const float* db = deltas + ((size_t)b_o*T_)*V_ + v_o;
        #pragma unroll
        for (int lt = 0; lt < PT_; ++lt) {
            xv[lt] = xb[lt*V_]; mv[lt] = mb[lt*V_]; dvv[lt] = db[lt*V_];
        }
    }
    u16x4 gdl0 = ((const u16x4*)gdv)[((size_t)(blk*4 + g8))*256 + c0];
    u16x4 gdl1 = ((const u16x4*)gdv)[((size_t)(blk*4 + g8))*256 + c1];

    for (int p = 0; p < NPH; ++p) {
        // ================= stage: impute + ffill + loss + xl tile
        if (own) {
            #pragma unroll
            for (int lt = 0; lt < PT_; ++lt) {
                float xt = xv[lt], m = mv[lt], d = dvv[lt];
                float gx = __expf(-fmaxf(fmaf(d, wxd, bx), 0.f));
                last = (m > 0.f) ? xt : last;
                float xu = gx*last + (1.f-gx)*mnv;
                float xh = m*xt + (1.f-m)*xu;
                ximp[((size_t)b_o*T_ + p*PT_ + lt)*V_ + v_o] = xh;
                int mr = r_o*4 + lt;
                int pk = __builtin_amdgcn_cvt_pk_fp8_f32(xh, m, 0, false);
                xl[mr*200 + v_o]      = (unsigned char)(pk & 0xFF);
                xl[mr*200 + V_ + v_o] = (unsigned char)((pk >> 8) & 0xFF);
                lossn[lt][tid] = fabsf(xt - xu)*m;
                lossd[lt][tid] = m;
            }
        }
        __syncthreads();

        // ---- loss reduce (wave 0)
        if (tid < 64) {
            int lt = tid >> 4, part = tid & 15;
            float n = 0.f, ds = 0.f;
            for (int j = part; j < 4*V_; j += 16) { n += lossn[lt][j]; ds += lossd[lt][j]; }
            n += __shfl_xor(n, 1); ds += __shfl_xor(ds, 1);
            n += __shfl_xor(n, 2); ds += __shfl_xor(ds, 2);
            n += __shfl_xor(n, 4); ds += __shfl_xor(ds, 4);
            n += __shfl_xor(n, 8); ds += __shfl_xor(ds, 8);
            if (part == 0) {
                int t = p*PT_ + lt;
                numpart[t*NB2 + blk] = n;
                denpart[t*NB2 + blk] = ds;
            }
        }

        // ================= gates GEMM: fp8, K=192, W_ih streamed (coalesced frag-major)
        f32x4 ar0 = {0.f,0.f,0.f,0.f}, az0 = ar0, an0 = ar0;
        f32x4 ar1 = ar0, az1 = ar0, an1 = ar0;
        #pragma unroll
        for (int kt = 0; kt < 6; ++kt) {
            long a = *(const long*)&xl[l15*200 + kt*32 + g8*8];
            ar0 = __builtin_amdgcn_mfma_f32_16x16x32_fp8_fp8(a, wT[iw0 +         kt*64], ar0, 0,0,0);
            az0 = __builtin_amdgcn_mfma_f32_16x16x32_fp8_fp8(a, wT[iw0 + 384 +   kt*64], az0, 0,0,0);
            an0 = __builtin_amdgcn_mfma_f32_16x16x32_fp8_fp8(a, wT[iw0 + 768 +   kt*64], an0, 0,0,0);
            ar1 = __builtin_amdgcn_mfma_f32_16x16x32_fp8_fp8(a, wT[iw1 +         kt*64], ar1, 0,0,0);
            az1 = __builtin_amdgcn_mfma_f32_16x16x32_fp8_fp8(a, wT[iw1 + 384 +   kt*64], az1, 0,0,0);
            an1 = __builtin_amdgcn_mfma_f32_16x16x32_fp8_fp8(a, wT[iw1 + 768 +   kt*64], an1, 0,0,0);
        }

        // ---- prefetch next phase's inputs + gamma (in flight under recurrence)
        if (p + 1 < NPH) {
            if (own) {
                const float* xb = x      + ((size_t)b_o*T_ + (p+1)*PT_)*V_ + v_o;
                const float* mb = mask   + ((size_t)b_o*T_ + (p+1)*PT_)*V_ + v_o;
                const float* db = deltas + ((size_t)b_o*T_ + (p+1)*PT_)*V_ + v_o;
                #pragma unroll
                for (int lt = 0; lt < PT_; ++lt) {
                    xv[lt] = xb[lt*V_]; mv[lt] = mb[lt*V_]; dvv[lt] = db[lt*V_];
                }
            }
        }
        u16x4 ngdl0 = gdl0, ngdl1 = gdl1;
        if (p + 1 < NPH) {
            ngdl0 = ((const u16x4*)gdv)[((size_t)((p+1)*1024 + blk*4 + g8))*256 + c0];
            ngdl1 = ((const u16x4*)gdv)[((size_t)((p+1)*1024 + blk*4 + g8))*256 + c1];
        }

        // ================= recurrence: 4 steps (r,z B-frags from LDS, n from regs)
        const unsigned char* wr0 = whL + (size_t)c0*256;
        const unsigned char* wr1 = whL + (size_t)(c0+128)*256;
        const unsigned char* wz0 = whL + (size_t)(c0+256)*256;
        const unsigned char* wz1 = whL + (size_t)(c0+384)*256;
        #pragma unroll
        for (int lt = 0; lt < PT_; ++lt) {
            const int cb = lt & 1;
            float hd0 = h0 * s2f(gdl0[lt]);
            float hd1 = h1 * s2f(gdl1[lt]);
            int pk = __builtin_amdgcn_cvt_pk_fp8_f32(hd0, hd1, 0, false);
            hlds[cb][g8*272 + c0] = (unsigned char)(pk & 0xFF);
            hlds[cb][g8*272 + c1] = (unsigned char)((pk >> 8) & 0xFF);
            __syncthreads();
            f32x4 s00 = {bhr0,bhr0,bhr0,bhr0};
            f32x4 s10 = {bhz0,bhz0,bhz0,bhz0};
            f32x4 s20 = {bhn0,bhn0,bhn0,bhn0};
            f32x4 s01 = {bhr1,bhr1,bhr1,bhr1};
            f32x4 s11 = {bhz1,bhz1,bhz1,bhz1};
            f32x4 s21 = {bhn1,bhn1,bhn1,bhn1};
            #pragma unroll
            for (int kt = 0; kt < 8; ++kt) {
                long a = *(const long*)&hlds[cb][(l15>>2)*272 + kt*32 + g8*8];
                int o = (kt*32 + g8*8) ^ mR;
                s00 = __builtin_amdgcn_mfma_f32_16x16x32_fp8_fp8(a, *(const long*)(wr0 + o), s00, 0,0,0);
                s01 = __builtin_amdgcn_mfma_f32_16x16x32_fp8_fp8(a, *(const long*)(wr1 + o), s01, 0,0,0);
                s10 = __builtin_amdgcn_mfma_f32_16x16x32_fp8_fp8(a, *(const long*)(wz0 + o), s10, 0,0,0);
                s11 = __builtin_amdgcn_mfma_f32_16x16x32_fp8_fp8(a, *(const long*)(wz1 + o), s11, 0,0,0);
                s20 = __builtin_amdgcn_mfma_f32_16x16x32_fp8_fp8(a, wfn0[kt], s20, 0,0,0);
                s21 = __builtin_amdgcn_mfma_f32_16x16x32_fp8_fp8(a, wfn1[kt], s21, 0,0,0);
            }
            float rg0 = sig_(ar0[lt] + s00[0]);
            float zg0 = sig_(az0[lt] + s10[0]);
            float ng0 = tanh_(an0[lt] + rg0*s20[0]);
            h0 = (1.f - zg0)*ng0 + zg0*hd0;
            float rg1 = sig_(ar1[lt] + s01[0]);
            float zg1 = sig_(az1[lt] + s11[0]);
            float ng1 = tanh_(an1[lt] + rg1*s21[0]);
            h1 = (1.f - zg1)*ng1 + zg1*hd1;
        }
        gdl0 = ngdl0; gdl1 = ngdl1;
    }

    // ================= epilogue
    {
        float pr = h0 * W_cls[c0] + h1 * W_cls[c1];
        pr += __shfl_xor(pr, 1);
        pr += __shfl_xor(pr, 2);
        pr += __shfl_xor(pr, 4);
        pr += __shfl_xor(pr, 8);
        if (l15 == 0) yred[g8][wv] = pr;
        __syncthreads();
        if (tid < 4) {
            float s = b_cls[0];
            #pragma unroll
            for (int ww = 0; ww < 8; ++ww) s += yred[tid][ww];
            yout[blk*4 + tid]   = s;
            yscore[blk*4 + tid] = 1.f/(1.f+__expf(-s));
        }
    }
}

// ---------------------------------------------------------------- loss stage 1
__global__ __launch_bounds__(256) void k_loss_t(
    const float* __restrict__ numpart, const float* __restrict__ denpart,
    float* __restrict__ tpart)
{
    int t = blockIdx.x, tid = threadIdx.x;
    float n = numpart[t*NB2 + tid];
    float d = denpart[t*NB2 + tid];
    for (int off = 32; off; off >>= 1) { n += __shfl_down(n, off); d += __shfl_down(d, off); }
    __shared__ float sn[4], sd[4];
    int lane = tid & 63, wid = tid >> 6;
    if (lane == 0) { sn[wid] = n; sd[wid] = d; }
    __syncthreads();
    if (tid == 0) {
        float nn = sn[0]+sn[1]+sn[2]+sn[3], dd = sd[0]+sd[1]+sd[2]+sd[3];
        tpart[t] = nn / (dd + 1e-5f);
    }
}

// ---------------------------------------------------------------- loss stage 2
__global__ __launch_bounds__(128) void k_loss_final(
    const float* __restrict__ tpart, float* __restrict__ out_loss)
{
    int tid = threadIdx.x;
    float s = tpart[tid];
    for (int off = 32; off; off >>= 1) s += __shfl_down(s, off);
    __shared__ float sp[2];
    if ((tid&63)==0) sp[tid>>6] = s;
    __syncthreads();
    if (tid==0) out_loss[0] = sp[0] + sp[1];
}

static inline size_t al256(size_t x){ return (x + 255) & ~(size_t)255; }

extern "C" void kernel_launch(void* const* d_in, const int* in_sizes, int n_in,
                              void* d_out, int out_size, void* d_ws, size_t ws_size,
                              hipStream_t stream)
{
    const float* x      = (const float*)d_in[0];
    const float* mask   = (const float*)d_in[1];
    const float* deltas = (const float*)d_in[2];
    const float* meanset= (const float*)d_in[3];
    const float* W_h    = (const float*)d_in[4];
    const float* b_h    = (const float*)d_in[5];
    const float* W_x    = (const float*)d_in[6];
    const float* b_x    = (const float*)d_in[7];
    const float* W_ih   = (const float*)d_in[8];
    const float* b_ih   = (const float*)d_in[9];
    const float* W_hh   = (const float*)d_in[10];
    const float* b_hh   = (const float*)d_in[11];
    const float* W_cls  = (const float*)d_in[12];
    const float* b_cls  = (const float*)d_in[13];

    float* out    = (float*)d_out;
    float* ximp   = out;                        // B*T*V
    float* xloss  = out + (size_t)B_*T_*V_;     // 1
    float* yout   = xloss + 1;                  // B
    float* yscore = yout + B_;                  // B

    size_t off = 0;
    size_t off_whh8 = off; off = al256(off + (size_t)768*256);      // fp8 linear
    size_t off_wih8 = off; off = al256(off + (size_t)768*192);      // fp8 frag-major
    size_t off_whp  = off; off = al256(off + (size_t)256*96*2);     // bf16, bias folded
    size_t off_gdv  = off; off = al256(off + (size_t)B_*T_*H_*2);   // gamma bf16 frag-native
    size_t off_np   = off; off = al256(off + (size_t)T_*NB2*4);
    size_t off_dp   = off; off = al256(off + (size_t)T_*NB2*4);
    size_t off_tp   = off; off = al256(off + (size_t)T_*4);
    if (off > ws_size) return;

    char* ws = (char*)d_ws;
    unsigned char* whh8 = (unsigned char*)(ws + off_whh8);
    unsigned char* wih8 = (unsigned char*)(ws + off_wih8);
    short* whp    = (short*)(ws + off_whp);
    unsigned short* gdv = (unsigned short*)(ws + off_gdv);
    float* numpart= (float*)(ws + off_np);
    float* denpart= (float*)(ws + off_dp);
    float* tpart  = (float*)(ws + off_tp);

    hipLaunchKernelGGL(k_cvt_fp8, dim3((768*256/4+255)/256), dim3(256), 0, stream, W_hh, whh8, 768*256);
    hipLaunchKernelGGL(k_prep_wih8, dim3((18432+255)/256), dim3(256), 0, stream, W_ih, b_ih, wih8);
    hipLaunchKernelGGL(k_prep_whp, dim3((256*96+255)/256), dim3(256), 0, stream, W_h, b_h, whp);
    hipLaunchKernelGGL(k_gammah, dim3(256, 32), dim3(256), 0, stream, deltas, whp, gdv);
    hipLaunchKernelGGL(k_fused, dim3(NB2), dim3(512), 0, stream,
                       x, mask, deltas, meanset, W_x, b_x,
                       wih8, whh8, gdv, b_hh, W_cls, b_cls,
                       ximp, numpart, denpart, yout, yscore);
    hipLaunchKernelGGL(k_loss_t, dim3(T_), dim3(256), 0, stream, numpart, denpart, tpart);
    hipLaunchKernelGGL(k_loss_final, dim3(1), dim3(128), 0, stream, tpart, xloss);
}

// Round 12
// 268.990 us; speedup vs baseline: 1.3777x; 1.3777x over previous
//
#include <hip/hip_runtime.h>

#define B_  1024
#define T_  128
#define V_  89
#define H_  256
#define NB2 256

typedef __attribute__((ext_vector_type(8))) short bf16x8;
typedef __attribute__((ext_vector_type(4))) float f32x4;
typedef __attribute__((ext_vector_type(4))) unsigned short u16x4;
typedef __attribute__((ext_vector_type(8))) int i32x8;
typedef __attribute__((ext_vector_type(4))) int i32x4;

__device__ __forceinline__ short f2bs(float f){
    unsigned u = __float_as_uint(f);
    unsigned r = (u + 0x7FFFu + ((u>>16)&1u)) >> 16;
    return (short)r;
}
__device__ __forceinline__ float s2f(unsigned short s){
    return __uint_as_float(((unsigned)s) << 16);
}
__device__ __forceinline__ float sig_(float x){ return 1.f/(1.f+__expf(-x)); }
__device__ __forceinline__ float tanh_(float x){ return 2.f/(1.f+__expf(-2.f*x)) - 1.f; }

// ---------------------------------------------------------------- W_hh fp32 -> fp8 [768][256]
__global__ __launch_bounds__(256) void k_cvt_fp8(
    const float* __restrict__ src, unsigned char* __restrict__ dst, int n)
{
    int i = blockIdx.x*256 + threadIdx.x;
    if (i*4 >= n) return;
    float f0 = src[i*4+0], f1 = src[i*4+1], f2 = src[i*4+2], f3 = src[i*4+3];
    int w = __builtin_amdgcn_cvt_pk_fp8_f32(f0, f1, 0, false);
    w     = __builtin_amdgcn_cvt_pk_fp8_f32(f2, f3, w, true);
    ((int*)dst)[i] = w;
}

// ---------------------------------------------------------------- W_ih+b_ih -> fp8 frag-major
// chunk idx = (((WV*3+g)*6+kt)*4+g8)*16+l15; 8 fp8 of row n=g*256+WV*16+l15, k=kt*32+g8*8..+7
// (k: 0..177 = W_ih, 178 = bias, else 0)
__global__ __launch_bounds__(256) void k_prep_wih8(
    const float* __restrict__ W_ih, const float* __restrict__ b_ih,
    unsigned char* __restrict__ dst)
{
    int i = blockIdx.x*256 + threadIdx.x;
    if (i >= 18432) return;
    int l15 = i & 15, t = i >> 4;
    int g8 = t & 3; t >>= 2;
    int kt = t % 6; t /= 6;
    int g = t % 3, WV = t / 3;
    int n = g*256 + WV*16 + l15;
    float f[8];
    #pragma unroll
    for (int j = 0; j < 8; ++j) {
        int k = kt*32 + g8*8 + j;
        f[j] = (k < 178) ? W_ih[(size_t)n*178 + k] : (k == 178 ? b_ih[n] : 0.f);
    }
    int w0 = __builtin_amdgcn_cvt_pk_fp8_f32(f[0], f[1], 0, false);
    w0     = __builtin_amdgcn_cvt_pk_fp8_f32(f[2], f[3], w0, true);
    int w1 = __builtin_amdgcn_cvt_pk_fp8_f32(f[4], f[5], 0, false);
    w1     = __builtin_amdgcn_cvt_pk_fp8_f32(f[6], f[7], w1, true);
    ((int*)dst)[i*2]   = w0;
    ((int*)dst)[i*2+1] = w1;
}

// ---------------------------------------------------------------- W_h+b_h -> bf16 [256][96]
__global__ __launch_bounds__(256) void k_prep_whp(
    const float* __restrict__ W_h, const float* __restrict__ b_h,
    short* __restrict__ dst)
{
    int i = blockIdx.x*256 + threadIdx.x;
    if (i >= 256*96) return;
    int n = i / 96, k = i - n*96;
    float v = (k < V_) ? W_h[(size_t)n*V_ + k] : (k == V_ ? b_h[n] : 0.f);
    dst[i] = f2bs(v);
}

// ---------------------------------------------------------------- k_prep: impute + gates + gamma
// 256 blocks x 512 thr. Block = 4 batch rows, phases of 4 t. Writes ushort4(r,z,n,gamma) bf16
// at word idx (((ltc*256+blk)*4+g8)*256 + col). M-tile = 4b x 4t (full M utilization).
__global__ __launch_bounds__(512) void k_prep(
    const float* __restrict__ x, const float* __restrict__ mask,
    const float* __restrict__ deltas, const float* __restrict__ meanset,
    const float* __restrict__ W_x, const float* __restrict__ b_x,
    const unsigned char* __restrict__ wihT, const short* __restrict__ whp,
    float* __restrict__ ximp, float* __restrict__ lastst,
    float* __restrict__ numpart, float* __restrict__ denpart,
    unsigned short* __restrict__ gi4, int t0, int TC, int first)
{
    __shared__ unsigned char xl[16*200] __attribute__((aligned(16)));
    __shared__ short dl2[16*104] __attribute__((aligned(16)));
    __shared__ float lossn[4][360], lossd[4][360];
    int tid = threadIdx.x, lane = tid & 63, wv = tid >> 6;
    int l15 = lane & 15, g8 = lane >> 4;
    int blk = blockIdx.x;

    for (int i = tid; i < 16*22; i += 512) {
        int r = i/22, k = 178 + (i - r*22);
        xl[r*200 + k] = (k == 178) ? 0x38 : 0;          // fp8(1.0) bias col
    }
    for (int i = tid; i < 16*15; i += 512) {
        int r = i/15, k = 89 + (i - r*15);
        dl2[r*104 + k] = (k == 89) ? (short)0x3F80 : (short)0;  // bf16(1.0) bias col
    }
    bool own = tid < 4*V_;
    int r_o = tid / V_, v_o = tid - r_o*V_, b_o = blk*4 + r_o;
    float wxd = 0.f, bx = 0.f, mnv = 0.f, lastv = 0.f;
    if (own) {
        wxd = W_x[v_o*V_ + v_o]; bx = b_x[v_o]; mnv = meanset[v_o];
        lastv = first ? 0.f : lastst[(size_t)b_o*V_ + v_o];
    }
    const long* wT = (const long*)wihT;

    int nph = TC >> 2;
    for (int p = 0; p < nph; ++p) {
        int tg = t0 + p*4;
        __syncthreads();               // prior phase's GEMM reads complete
        if (own) {
            const float* xb = x      + ((size_t)b_o*T_ + tg)*V_ + v_o;
            const float* mb = mask   + ((size_t)b_o*T_ + tg)*V_ + v_o;
            const float* db = deltas + ((size_t)b_o*T_ + tg)*V_ + v_o;
            float xv[4], mv[4], dv[4];
            #pragma unroll
            for (int lt = 0; lt < 4; ++lt) {
                xv[lt] = xb[lt*V_]; mv[lt] = mb[lt*V_]; dv[lt] = db[lt*V_];
            }
            #pragma unroll
            for (int lt = 0; lt < 4; ++lt) {
                float xt = xv[lt], m = mv[lt], d = dv[lt];
                float gx = __expf(-fmaxf(fmaf(d, wxd, bx), 0.f));
                lastv = (m > 0.f) ? xt : lastv;
                float xu = gx*lastv + (1.f-gx)*mnv;
                float xh = m*xt + (1.f-m)*xu;
                ximp[((size_t)b_o*T_ + tg + lt)*V_ + v_o] = xh;
                int mr = r_o*4 + lt;
                int pk = __builtin_amdgcn_cvt_pk_fp8_f32(xh, m, 0, false);
                xl[mr*200 + v_o]      = (unsigned char)(pk & 0xFF);
                xl[mr*200 + V_ + v_o] = (unsigned char)((pk >> 8) & 0xFF);
                dl2[mr*104 + v_o]     = f2bs(d);
                lossn[lt][tid] = fabsf(xt - xu)*m;
                lossd[lt][tid] = m;
            }
        }
        __syncthreads();
        if (tid < 64) {
            int lt = tid >> 4, part = tid & 15;
            float n = 0.f, ds = 0.f;
            for (int j = part; j < 4*V_; j += 16) { n += lossn[lt][j]; ds += lossd[lt][j]; }
            n += __shfl_xor(n, 1); ds += __shfl_xor(ds, 1);
            n += __shfl_xor(n, 2); ds += __shfl_xor(ds, 2);
            n += __shfl_xor(n, 4); ds += __shfl_xor(ds, 4);
            n += __shfl_xor(n, 8); ds += __shfl_xor(ds, 8);
            if (part == 0) {
                numpart[(size_t)(tg+lt)*NB2 + blk] = n;
                denpart[(size_t)(tg+lt)*NB2 + blk] = ds;
            }
        }
        #pragma unroll
        for (int s = 0; s < 2; ++s) {
            int cset = wv + s*8;
            size_t iw = (size_t)cset*1152 + g8*16 + l15;
            f32x4 ar = {0.f,0.f,0.f,0.f}, az = ar, an = ar, ga = ar;
            #pragma unroll
            for (int kt = 0; kt < 6; ++kt) {
                long a = *(const long*)&xl[l15*200 + kt*32 + g8*8];
                ar = __builtin_amdgcn_mfma_f32_16x16x32_fp8_fp8(a, wT[iw +       kt*64], ar, 0,0,0);
                az = __builtin_amdgcn_mfma_f32_16x16x32_fp8_fp8(a, wT[iw + 384 + kt*64], az, 0,0,0);
                an = __builtin_amdgcn_mfma_f32_16x16x32_fp8_fp8(a, wT[iw + 768 + kt*64], an, 0,0,0);
            }
            int cg = cset*16 + l15;
            #pragma unroll
            for (int kt = 0; kt < 3; ++kt) {
                bf16x8 da = *(const bf16x8*)&dl2[l15*104 + kt*32 + g8*8];
                bf16x8 gw = *(const bf16x8*)(whp + (size_t)cg*96 + kt*32 + g8*8);
                ga = __builtin_amdgcn_mfma_f32_16x16x32_bf16(da, gw, ga, 0,0,0);
            }
            #pragma unroll
            for (int rr = 0; rr < 4; ++rr) {
                int ltc = p*4 + rr;
                u16x4 v;
                v[0] = (unsigned short)f2bs(ar[rr]);
                v[1] = (unsigned short)f2bs(az[rr]);
                v[2] = (unsigned short)f2bs(an[rr]);
                v[3] = (unsigned short)f2bs(__expf(-fmaxf(ga[rr], 0.f)));
                ((u16x4*)gi4)[(((size_t)ltc*256 + blk)*4 + g8)*256 + cg] = v;
            }
        }
    }
    if (own) lastst[(size_t)b_o*V_ + v_o] = lastv;
}

// ---------------------------------------------------------------- k_recur: pure recurrence
// 256 blocks x 512 thr. Lane owns (batch g8, cols c0 = wv*16+l15, c1 = c0+128).
// r-gate W in LDS (16B-XOR swizzle, 2-way max); z,n gates register-resident i32x8.
// S-GEMM via mfma_scale 16x16x128 fp8 (scales = 1.0).
__global__ __launch_bounds__(512) void k_recur(
    const unsigned short* __restrict__ gi4, const unsigned char* __restrict__ whh8,
    const float* __restrict__ b_hh, const float* __restrict__ W_cls,
    const float* __restrict__ b_cls,
    float* __restrict__ hstate, float* __restrict__ yout, float* __restrict__ yscore,
    int TC, int first, int last)
{
    __shared__ unsigned char whL[256*256];                              // r-gate, swizzled
    __shared__ unsigned char hlds[2][4*272] __attribute__((aligned(16)));
    __shared__ float yred[4][8];

    int tid = threadIdx.x, lane = tid & 63, wv = tid >> 6;
    int l15 = lane & 15, g8 = lane >> 4;
    int blk = blockIdx.x;
    int c0 = wv*16 + l15, c1 = c0 + 128;

    // stage r-gate rows 0..255 with 16B-granular XOR swizzle
    for (int it = 0; it < 16; ++it) {
        int idx = it*512 + tid;            // 8192 chunks of 8B
        int row = idx >> 5, j = idx & 31;
        long v = *(const long*)(whh8 + (size_t)row*256 + j*8);
        *(long*)&whL[row*256 + ((j*8) ^ ((row & 15) << 4))] = v;
    }
    // z,n gates register-resident
    i32x8 wz[2][2], wn[2][2];
    #pragma unroll
    for (int s = 0; s < 2; ++s) {
        int cs16 = (wv + s*8)*16 + l15;
        #pragma unroll
        for (int k2 = 0; k2 < 2; ++k2) {
            wz[s][k2] = *(const i32x8*)(whh8 + (size_t)(256 + cs16)*256 + k2*128 + g8*32);
            wn[s][k2] = *(const i32x8*)(whh8 + (size_t)(512 + cs16)*256 + k2*128 + g8*32);
        }
    }
    float bhr[2], bhz[2], bhn[2];
    #pragma unroll
    for (int s = 0; s < 2; ++s) {
        int cs16 = (wv + s*8)*16 + l15;
        bhr[s] = b_hh[cs16]; bhz[s] = b_hh[256 + cs16]; bhn[s] = b_hh[512 + cs16];
    }

    float h0 = first ? 0.f : hstate[(size_t)(blk*4 + g8)*H_ + c0];
    float h1 = first ? 0.f : hstate[(size_t)(blk*4 + g8)*H_ + c1];

    __syncthreads();   // whL staged

    const u16x4* gp = (const u16x4*)gi4;
#define GIDX(LT,C) ((((size_t)(LT)*256 + blk)*4 + g8)*256 + (C))
    u16x4 gv0 = gp[GIDX(0, c0)], gv1 = gp[GIDX(0, c1)];

    for (int lt = 0; lt < TC; ++lt) {
        int cb = lt & 1;
        float hd0 = h0 * s2f(gv0[3]);
        float hd1 = h1 * s2f(gv1[3]);
        int pk = __builtin_amdgcn_cvt_pk_fp8_f32(hd0, hd1, 0, false);
        hlds[cb][g8*272 + c0] = (unsigned char)(pk & 0xFF);
        hlds[cb][g8*272 + c1] = (unsigned char)((pk >> 8) & 0xFF);
        __syncthreads();
        // A fragments (rows replicated via read: row l15 -> batch l15>>2)
        i32x8 A[2];
        #pragma unroll
        for (int k2 = 0; k2 < 2; ++k2) {
            const unsigned char* ap = &hlds[cb][(l15 >> 2)*272 + k2*128 + g8*32];
            i32x4 lo = *(const i32x4*)(ap);
            i32x4 hi = *(const i32x4*)(ap + 16);
            i32x8 a; a[0]=lo[0]; a[1]=lo[1]; a[2]=lo[2]; a[3]=lo[3];
                     a[4]=hi[0]; a[5]=hi[1]; a[6]=hi[2]; a[7]=hi[3];
            A[k2] = a;
        }
        // prefetch next step's gate word
        u16x4 ngv0 = gv0, ngv1 = gv1;
        if (lt + 1 < TC) { ngv0 = gp[GIDX(lt+1, c0)]; ngv1 = gp[GIDX(lt+1, c1)]; }
        int sw = l15 << 4;
        #pragma unroll
        for (int s = 0; s < 2; ++s) {
            const unsigned char* wb = &whL[(size_t)((wv + s*8)*16 + l15)*256];
            f32x4 sr = {bhr[s],bhr[s],bhr[s],bhr[s]};
            f32x4 sz = {bhz[s],bhz[s],bhz[s],bhz[s]};
            f32x4 sn = {bhn[s],bhn[s],bhn[s],bhn[s]};
            #pragma unroll
            for (int k2 = 0; k2 < 2; ++k2) {
                int ob = k2*128 + g8*32;
                i32x4 blo = *(const i32x4*)(wb + ((ob     ) ^ sw));
                i32x4 bhi = *(const i32x4*)(wb + ((ob + 16) ^ sw));
                i32x8 b; b[0]=blo[0]; b[1]=blo[1]; b[2]=blo[2]; b[3]=blo[3];
                         b[4]=bhi[0]; b[5]=bhi[1]; b[6]=bhi[2]; b[7]=bhi[3];
                sr = __builtin_amdgcn_mfma_scale_f32_16x16x128_f8f6f4(A[k2], b,         sr, 0,0, 0,0x7F7F7F7F, 0,0x7F7F7F7F);
                sz = __builtin_amdgcn_mfma_scale_f32_16x16x128_f8f6f4(A[k2], wz[s][k2], sz, 0,0, 0,0x7F7F7F7F, 0,0x7F7F7F7F);
                sn = __builtin_amdgcn_mfma_scale_f32_16x16x128_f8f6f4(A[k2], wn[s][k2], sn, 0,0, 0,0x7F7F7F7F, 0,0x7F7F7F7F);
            }
            if (s == 0) {
                float rg = sig_(s2f(gv0[0]) + sr[0]);
                float zg = sig_(s2f(gv0[1]) + sz[0]);
                float ng = tanh_(s2f(gv0[2]) + rg*sn[0]);
                h0 = (1.f - zg)*ng + zg*hd0;
            } else {
                float rg = sig_(s2f(gv1[0]) + sr[0]);
                float zg = sig_(s2f(gv1[1]) + sz[0]);
                float ng = tanh_(s2f(gv1[2]) + rg*sn[0]);
                h1 = (1.f - zg)*ng + zg*hd1;
            }
        }
        gv0 = ngv0; gv1 = ngv1;
    }
#undef GIDX

    hstate[(size_t)(blk*4 + g8)*H_ + c0] = h0;
    hstate[(size_t)(blk*4 + g8)*H_ + c1] = h1;

    if (last) {
        float pr = h0 * W_cls[c0] + h1 * W_cls[c1];
        pr += __shfl_xor(pr, 1);
        pr += __shfl_xor(pr, 2);
        pr += __shfl_xor(pr, 4);
        pr += __shfl_xor(pr, 8);
        if (l15 == 0) yred[g8][wv] = pr;
        __syncthreads();
        if (tid < 4) {
            float sacc = b_cls[0];
            #pragma unroll
            for (int ww = 0; ww < 8; ++ww) sacc += yred[tid][ww];
            yout[blk*4 + tid]   = sacc;
            yscore[blk*4 + tid] = 1.f/(1.f+__expf(-sacc));
        }
    }
}

// ---------------------------------------------------------------- loss stage 1
__global__ __launch_bounds__(256) void k_loss_t(
    const float* __restrict__ numpart, const float* __restrict__ denpart,
    float* __restrict__ tpart)
{
    int t = blockIdx.x, tid = threadIdx.x;
    float n = numpart[(size_t)t*NB2 + tid];
    float d = denpart[(size_t)t*NB2 + tid];
    for (int off = 32; off; off >>= 1) { n += __shfl_down(n, off); d += __shfl_down(d, off); }
    __shared__ float sn[4], sd[4];
    int lane = tid & 63, wid = tid >> 6;
    if (lane == 0) { sn[wid] = n; sd[wid] = d; }
    __syncthreads();
    if (tid == 0) {
        float nn = sn[0]+sn[1]+sn[2]+sn[3], dd = sd[0]+sd[1]+sd[2]+sd[3];
        tpart[t] = nn / (dd + 1e-5f);
    }
}

// ---------------------------------------------------------------- loss stage 2
__global__ __launch_bounds__(128) void k_loss_final(
    const float* __restrict__ tpart, float* __restrict__ out_loss)
{
    int tid = threadIdx.x;
    float s = tpart[tid];
    for (int off = 32; off; off >>= 1) s += __shfl_down(s, off);
    __shared__ float sp[2];
    if ((tid&63)==0) sp[tid>>6] = s;
    __syncthreads();
    if (tid==0) out_loss[0] = sp[0] + sp[1];
}

static inline size_t al256(size_t x){ return (x + 255) & ~(size_t)255; }

extern "C" void kernel_launch(void* const* d_in, const int* in_sizes, int n_in,
                              void* d_out, int out_size, void* d_ws, size_t ws_size,
                              hipStream_t stream)
{
    const float* x      = (const float*)d_in[0];
    const float* mask   = (const float*)d_in[1];
    const float* deltas = (const float*)d_in[2];
    const float* meanset= (const float*)d_in[3];
    const float* W_h    = (const float*)d_in[4];
    const float* b_h    = (const float*)d_in[5];
    const float* W_x    = (const float*)d_in[6];
    const float* b_x    = (const float*)d_in[7];
    const float* W_ih   = (const float*)d_in[8];
    const float* b_ih   = (const float*)d_in[9];
    const float* W_hh   = (const float*)d_in[10];
    const float* b_hh   = (const float*)d_in[11];
    const float* W_cls  = (const float*)d_in[12];
    const float* b_cls  = (const float*)d_in[13];

    float* out    = (float*)d_out;
    float* ximp   = out;                        // B*T*V
    float* xloss  = out + (size_t)B_*T_*V_;     // 1
    float* yout   = xloss + 1;                  // B
    float* yscore = yout + B_;                  // B

    size_t off = 0;
    size_t off_whh8 = off; off = al256(off + (size_t)768*256);
    size_t off_wihT = off; off = al256(off + (size_t)768*192);
    size_t off_whp  = off; off = al256(off + (size_t)256*96*2);
    size_t off_last = off; off = al256(off + (size_t)B_*V_*4);
    size_t off_h    = off; off = al256(off + (size_t)B_*H_*4);
    size_t off_np   = off; off = al256(off + (size_t)T_*NB2*4);
    size_t off_dp   = off; off = al256(off + (size_t)T_*NB2*4);
    size_t off_tp   = off; off = al256(off + (size_t)T_*4);
    size_t off_gi4  = off;

    int tcShift = -1;
    for (int s = 7; s >= 2; --s) {
        size_t gib = (size_t)(1 << s) * 256 * 4 * 256 * 8;  // TC * blk * g8 * col * 8B
        if (off_gi4 + gib <= ws_size) { tcShift = s; break; }
    }
    if (tcShift < 0) return;
    int TC = 1 << tcShift;
    int NC = T_ / TC;

    char* ws = (char*)d_ws;
    unsigned char* whh8 = (unsigned char*)(ws + off_whh8);
    unsigned char* wihT = (unsigned char*)(ws + off_wihT);
    short* whp    = (short*)(ws + off_whp);
    float* lastst = (float*)(ws + off_last);
    float* hstate = (float*)(ws + off_h);
    float* numpart= (float*)(ws + off_np);
    float* denpart= (float*)(ws + off_dp);
    float* tpart  = (float*)(ws + off_tp);
    unsigned short* gi4 = (unsigned short*)(ws + off_gi4);

    hipLaunchKernelGGL(k_cvt_fp8, dim3((768*256/4+255)/256), dim3(256), 0, stream, W_hh, whh8, 768*256);
    hipLaunchKernelGGL(k_prep_wih8, dim3((18432+255)/256), dim3(256), 0, stream, W_ih, b_ih, wihT);
    hipLaunchKernelGGL(k_prep_whp, dim3((256*96+255)/256), dim3(256), 0, stream, W_h, b_h, whp);

    for (int ci = 0; ci < NC; ++ci) {
        int t0 = ci * TC;
        hipLaunchKernelGGL(k_prep, dim3(256), dim3(512), 0, stream,
                           x, mask, deltas, meanset, W_x, b_x, wihT, whp,
                           ximp, lastst, numpart, denpart, gi4, t0, TC, ci==0);
        hipLaunchKernelGGL(k_recur, dim3(256), dim3(512), 0, stream,
                           gi4, whh8, b_hh, W_cls, b_cls,
                           hstate, yout, yscore, TC, ci==0, ci==NC-1);
    }
    hipLaunchKernelGGL(k_loss_t, dim3(T_), dim3(256), 0, stream, numpart, denpart, tpart);
    hipLaunchKernelGGL(k_loss_final, dim3(1), dim3(128), 0, stream, tpart, xloss);
}